// Round 3
// baseline (702.294 us; speedup 1.0000x reference)
//
#include <hip/hip_runtime.h>
#include <hip/hip_bf16.h>

// GCN encoder: out = concat(h1, h2), h_l = relu(Dinv(A+I)Dinv (x@W_l) + b_l)
// Inputs: x[N,128], W1,W2[128,128], b1,b2[128] = float32; edge_index int32 [2,E]
// Output: float32 [N,256] (harness compares vs bf16-emulated np ref, 2% rel).
//
// Pipeline: CSR build (by dst) -> per layer: row-parallel MFMA GEMM with
// dinv[row] pre-scaling (g = bf16((x@W)*dinv)) -> gather-aggregate per node:
// out[n] = relu(dinv[n]*(g[n] + sum_{s in N(n)} g[s]) + b). Deterministic,
// no float atomics.
//
// ws layout (bytes), total ~35 MB:
#define OFF_CNT  0x000000   // int[N]      in-degree counts (memset 0)
#define OFF_CUR  0x080000   // int[N]      bucket cursors
#define OFF_RP   0x100000   // int[N+1]    CSR row pointers
#define OFF_BSUM 0x180000   // int[512]    scan block sums
#define OFF_DINV 0x1C0000   // float[N]    rsqrt(deg+1)
#define OFF_COL  0x240000   // int[E]      CSR column (src) ids
#define OFF_WT1  0x8C0000   // bf16[128*128]  W1^T
#define OFF_WT2  0x8D0000   // bf16[128*128]  W2^T
#define OFF_G    0x900000   // bf16[N*128]    scaled GEMM output

typedef short bf16x8 __attribute__((ext_vector_type(8)));
typedef float f32x4 __attribute__((ext_vector_type(4)));
typedef float f32x2 __attribute__((ext_vector_type(2)));

static __device__ __forceinline__ float bf2f(unsigned int s) {
    return __uint_as_float(s << 16);
}
static __device__ __forceinline__ unsigned short f2bf(float f) {
    unsigned int u = __float_as_uint(f);
    u = u + 0x7fffu + ((u >> 16) & 1u);   // round-to-nearest-even
    return (unsigned short)(u >> 16);
}

// ---------- CSR build ----------
__global__ void count_k(const int* __restrict__ dst, int* __restrict__ cnt, int E) {
    int e = blockIdx.x * blockDim.x + threadIdx.x;
    if (e < E) atomicAdd(&cnt[dst[e]], 1);
}

__global__ void scan1_k(const int* __restrict__ cnt, int* __restrict__ rp,
                        int* __restrict__ bsum, int N) {
    __shared__ int sh[256];
    int i = blockIdx.x * 256 + threadIdx.x;
    int v = (i < N) ? cnt[i] : 0;
    sh[threadIdx.x] = v;
    __syncthreads();
    for (int off = 1; off < 256; off <<= 1) {
        int t = (threadIdx.x >= off) ? sh[threadIdx.x - off] : 0;
        __syncthreads();
        sh[threadIdx.x] += t;
        __syncthreads();
    }
    if (i < N) rp[i] = sh[threadIdx.x] - v;   // exclusive within block
    if (threadIdx.x == 255) bsum[blockIdx.x] = sh[255];
}

__global__ void scan2_k(int* __restrict__ bsum, int NB) {
    __shared__ int sh[512];
    int v = (threadIdx.x < NB) ? bsum[threadIdx.x] : 0;
    sh[threadIdx.x] = v;
    __syncthreads();
    for (int off = 1; off < 512; off <<= 1) {
        int t = (threadIdx.x >= off) ? sh[threadIdx.x - off] : 0;
        __syncthreads();
        sh[threadIdx.x] += t;
        __syncthreads();
    }
    if (threadIdx.x < NB) bsum[threadIdx.x] = sh[threadIdx.x] - v;  // exclusive
}

__global__ void scan3_k(int* __restrict__ rp, const int* __restrict__ bsum,
                        const int* __restrict__ cnt, int* __restrict__ cur,
                        float* __restrict__ dinv, int N, int E) {
    int i = blockIdx.x * 256 + threadIdx.x;
    if (i < N) {
        int v = rp[i] + bsum[i >> 8];
        rp[i] = v;
        cur[i] = v;
        dinv[i] = rsqrtf((float)(cnt[i] + 1));
    } else if (i == N) {
        rp[N] = E;
    }
}

__global__ void fill_k(const int* __restrict__ src, const int* __restrict__ dst,
                       int* __restrict__ cur, int* __restrict__ col, int E) {
    int e = blockIdx.x * blockDim.x + threadIdx.x;
    if (e < E) {
        int d = dst[e];
        int p = atomicAdd(&cur[d], 1);
        col[p] = src[e];
    }
}

// ---------- transpose + cvt W (128x128 f32 -> bf16) ----------
__global__ void transpose_w(const float* __restrict__ W,
                            unsigned short* __restrict__ WT) {
    int idx = blockIdx.x * 256 + threadIdx.x;   // grid 64 -> 16384
    int n = idx >> 7, k = idx & 127;
    WT[idx] = f2bf(W[k * 128 + n]);
}

// ---------- GEMM: G[r,:] = bf16( (A[r,:] @ W) * dinv[r] ) ----------
// A is float32 [M, lda]
__global__ __launch_bounds__(256) void gemm_scale(
    const float* __restrict__ A, int lda,
    const unsigned short* __restrict__ WT,
    const float* __restrict__ dinv,
    unsigned short* __restrict__ G, int M) {
    int wave = threadIdx.x >> 6;
    int lane = threadIdx.x & 63;
    int quad = lane >> 4;
    int l16  = lane & 15;
    int rowBase = blockIdx.x * 64 + wave * 16;
    int rowc = rowBase + l16;
    if (rowc > M - 1) rowc = M - 1;

    f32x4 acc[8];
#pragma unroll
    for (int t = 0; t < 8; t++) acc[t] = (f32x4){0.f, 0.f, 0.f, 0.f};

#pragma unroll
    for (int kk = 0; kk < 128; kk += 32) {
        const f32x4* ap = (const f32x4*)(A + (size_t)rowc * lda + kk + quad * 8);
        f32x4 a0 = ap[0], a1 = ap[1];
        bf16x8 a;
#pragma unroll
        for (int j = 0; j < 4; j++) {
            a[j]     = (short)f2bf(a0[j]);
            a[j + 4] = (short)f2bf(a1[j]);
        }
#pragma unroll
        for (int t = 0; t < 8; t++) {
            bf16x8 b = *(const bf16x8*)(WT + (t * 16 + l16) * 128 + kk + quad * 8);
            acc[t] = __builtin_amdgcn_mfma_f32_16x16x32_bf16(a, b, acc[t], 0, 0, 0);
        }
    }
    // D layout: row = quad*4 + reg, col = l16 (within each 16x16 tile t)
#pragma unroll
    for (int r = 0; r < 4; r++) {
        int orow = rowBase + quad * 4 + r;
        if (orow < M) {
            float di = dinv[orow];
#pragma unroll
            for (int t = 0; t < 8; t++) {
                G[(size_t)orow * 128 + t * 16 + l16] = f2bf(acc[t][r] * di);
            }
        }
    }
}

// ---------- Aggregate: out[n,:] = relu(dinv[n]*(g[n,:]+sum_{s in N(n)} g[s,:]) + b) ----------
// one wave per node; lane handles 2 channels; f32 output
__global__ __launch_bounds__(256) void agg_k(
    const unsigned short* __restrict__ G,
    const int* __restrict__ rp, const int* __restrict__ col,
    const float* __restrict__ dinv, const float* __restrict__ bias,
    float* __restrict__ Out, int colbase, int N) {
    int gid = (blockIdx.x * blockDim.x + threadIdx.x) >> 6;
    if (gid >= N) return;
    int lane = threadIdx.x & 63;

    unsigned int sv = *(const unsigned int*)(G + (size_t)gid * 128 + lane * 2);
    float a0 = bf2f(sv & 0xffffu), a1 = bf2f(sv >> 16);

    int e0 = rp[gid], e1 = rp[gid + 1];
    for (int e = e0; e < e1; e++) {
        int s = col[e];
        unsigned int v = *(const unsigned int*)(G + (size_t)s * 128 + lane * 2);
        a0 += bf2f(v & 0xffffu);
        a1 += bf2f(v >> 16);
    }
    float di = dinv[gid];
    f32x2 o;
    o[0] = fmaxf(a0 * di + bias[lane * 2], 0.f);
    o[1] = fmaxf(a1 * di + bias[lane * 2 + 1], 0.f);
    *(f32x2*)(Out + (size_t)gid * 256 + colbase + lane * 2) = o;
}

extern "C" void kernel_launch(void* const* d_in, const int* in_sizes, int n_in,
                              void* d_out, int out_size, void* d_ws, size_t ws_size,
                              hipStream_t stream) {
    const float* x  = (const float*)d_in[0];   // [N,128] f32
    const float* W1 = (const float*)d_in[1];   // [128,128] f32
    const float* b1 = (const float*)d_in[2];   // [128] f32
    const float* W2 = (const float*)d_in[3];
    const float* b2 = (const float*)d_in[4];
    const int* ei = (const int*)d_in[5];       // [2,E] int32

    const int N = in_sizes[0] / 128;
    const int E = in_sizes[5] / 2;
    const int* src = ei;
    const int* dst = ei + E;

    char* ws = (char*)d_ws;
    int*   cnt  = (int*)(ws + OFF_CNT);
    int*   cur  = (int*)(ws + OFF_CUR);
    int*   rp   = (int*)(ws + OFF_RP);
    int*   bsum = (int*)(ws + OFF_BSUM);
    float* dinv = (float*)(ws + OFF_DINV);
    int*   col  = (int*)(ws + OFF_COL);
    unsigned short* WT1 = (unsigned short*)(ws + OFF_WT1);
    unsigned short* WT2 = (unsigned short*)(ws + OFF_WT2);
    unsigned short* G   = (unsigned short*)(ws + OFF_G);
    float* out = (float*)d_out;

    hipMemsetAsync(cnt, 0, (size_t)N * sizeof(int), stream);

    transpose_w<<<64, 256, 0, stream>>>(W1, WT1);
    transpose_w<<<64, 256, 0, stream>>>(W2, WT2);

    int ceb = (E + 255) / 256;
    count_k<<<ceb, 256, 0, stream>>>(dst, cnt, E);

    int nb = (N + 255) / 256;
    scan1_k<<<nb, 256, 0, stream>>>(cnt, rp, bsum, N);
    scan2_k<<<1, 512, 0, stream>>>(bsum, nb);
    int nb1 = (N + 1 + 255) / 256;
    scan3_k<<<nb1, 256, 0, stream>>>(rp, bsum, cnt, cur, dinv, N, E);
    fill_k<<<ceb, 256, 0, stream>>>(src, dst, cur, col, E);

    int gb = (N + 63) / 64;
    int ab = (N + 3) / 4;

    // Layer 1 (A = x)
    gemm_scale<<<gb, 256, 0, stream>>>(x, 128, WT1, dinv, G, N);
    agg_k<<<ab, 256, 0, stream>>>(G, rp, col, dinv, b1, out, 0, N);
    // Layer 2 (A = h1 stored in out cols [0,128), f32, row stride 256)
    gemm_scale<<<gb, 256, 0, stream>>>(out, 256, WT2, dinv, G, N);
    agg_k<<<ab, 256, 0, stream>>>(G, rp, col, dinv, b2, out, 128, N);
}

// Round 4
// 530.828 us; speedup vs baseline: 1.3230x; 1.3230x over previous
//
#include <hip/hip_runtime.h>
#include <hip/hip_bf16.h>

// GCN encoder: out = concat(h1, h2), h_l = relu(Dinv(A+I)Dinv (x@W_l) + b_l)
// Inputs: x[N,128], W1,W2[128,128], b1,b2[128] = float32; edge_index int32 [2,E]
// Output: float32 [N,256] (harness compares vs bf16-emulated np ref, 2% rel).
//
// Round 4: agg_k v2 — 16B bf16x8 gather loads, 8 edges in flight/wave,
// shfl_xor butterfly across 4 lane-groups; layer-1 agg also emits bf16 H1
// so layer-2 GEMM reads 25.6MB instead of 102MB.
//
// ws layout (bytes):
#define OFF_CNT  0x000000    // int[N]      in-degree counts (memset 0)
#define OFF_CUR  0x080000    // int[N]      bucket cursors
#define OFF_RP   0x100000    // int[N+1]    CSR row pointers
#define OFF_BSUM 0x180000    // int[512]    scan block sums
#define OFF_DINV 0x1C0000    // float[N]    rsqrt(deg+1)
#define OFF_COL  0x240000    // int[E]      CSR column (src) ids
#define OFF_WT1  0x8C0000    // bf16[128*128]  W1^T
#define OFF_WT2  0x8D0000    // bf16[128*128]  W2^T
#define OFF_G    0x900000    // bf16[N*128]    scaled GEMM output (~25.6MB)
#define OFF_H1   0x2200000   // bf16[N*128]    h1 staged for layer-2 GEMM
#define WS_NEED  0x3A80000   // ~61.3MB if H1 used

typedef short bf16x8 __attribute__((ext_vector_type(8)));
typedef float f32x4 __attribute__((ext_vector_type(4)));
typedef unsigned int u32x4 __attribute__((ext_vector_type(4)));

static __device__ __forceinline__ unsigned short f2bf(float f) {
    unsigned int u = __float_as_uint(f);
    u = u + 0x7fffu + ((u >> 16) & 1u);   // round-to-nearest-even
    return (unsigned short)(u >> 16);
}

// ---------- CSR build ----------
__global__ void count_k(const int* __restrict__ dst, int* __restrict__ cnt, int E) {
    int e = blockIdx.x * blockDim.x + threadIdx.x;
    if (e < E) atomicAdd(&cnt[dst[e]], 1);
}

__global__ void scan1_k(const int* __restrict__ cnt, int* __restrict__ rp,
                        int* __restrict__ bsum, int N) {
    __shared__ int sh[256];
    int i = blockIdx.x * 256 + threadIdx.x;
    int v = (i < N) ? cnt[i] : 0;
    sh[threadIdx.x] = v;
    __syncthreads();
    for (int off = 1; off < 256; off <<= 1) {
        int t = (threadIdx.x >= off) ? sh[threadIdx.x - off] : 0;
        __syncthreads();
        sh[threadIdx.x] += t;
        __syncthreads();
    }
    if (i < N) rp[i] = sh[threadIdx.x] - v;   // exclusive within block
    if (threadIdx.x == 255) bsum[blockIdx.x] = sh[255];
}

__global__ void scan2_k(int* __restrict__ bsum, int NB) {
    __shared__ int sh[512];
    int v = (threadIdx.x < NB) ? bsum[threadIdx.x] : 0;
    sh[threadIdx.x] = v;
    __syncthreads();
    for (int off = 1; off < 512; off <<= 1) {
        int t = (threadIdx.x >= off) ? sh[threadIdx.x - off] : 0;
        __syncthreads();
        sh[threadIdx.x] += t;
        __syncthreads();
    }
    if (threadIdx.x < NB) bsum[threadIdx.x] = sh[threadIdx.x] - v;  // exclusive
}

__global__ void scan3_k(int* __restrict__ rp, const int* __restrict__ bsum,
                        const int* __restrict__ cnt, int* __restrict__ cur,
                        float* __restrict__ dinv, int N, int E) {
    int i = blockIdx.x * 256 + threadIdx.x;
    if (i < N) {
        int v = rp[i] + bsum[i >> 8];
        rp[i] = v;
        cur[i] = v;
        dinv[i] = rsqrtf((float)(cnt[i] + 1));
    } else if (i == N) {
        rp[N] = E;
    }
}

__global__ void fill_k(const int* __restrict__ src, const int* __restrict__ dst,
                       int* __restrict__ cur, int* __restrict__ col, int E) {
    int e = blockIdx.x * blockDim.x + threadIdx.x;
    if (e < E) {
        int d = dst[e];
        int p = atomicAdd(&cur[d], 1);
        col[p] = src[e];
    }
}

// ---------- transpose + cvt W (128x128 f32 -> bf16) ----------
__global__ void transpose_w(const float* __restrict__ W,
                            unsigned short* __restrict__ WT) {
    int idx = blockIdx.x * 256 + threadIdx.x;   // grid 64 -> 16384
    int n = idx >> 7, k = idx & 127;
    WT[idx] = f2bf(W[k * 128 + n]);
}

// ---------- GEMM: G[r,:] = bf16( (A[r,:] @ W) * dinv[r] ) ----------
// AF32=1: A is float32 [M,lda]; AF32=0: A is bf16 (ushort) [M,lda]
template <int AF32>
__global__ __launch_bounds__(256) void gemm_scale(
    const void* __restrict__ Av, int lda,
    const unsigned short* __restrict__ WT,
    const float* __restrict__ dinv,
    unsigned short* __restrict__ G, int M) {
    int wave = threadIdx.x >> 6;
    int lane = threadIdx.x & 63;
    int quad = lane >> 4;
    int l16  = lane & 15;
    int rowBase = blockIdx.x * 64 + wave * 16;
    int rowc = rowBase + l16;
    if (rowc > M - 1) rowc = M - 1;

    f32x4 acc[8];
#pragma unroll
    for (int t = 0; t < 8; t++) acc[t] = (f32x4){0.f, 0.f, 0.f, 0.f};

#pragma unroll
    for (int kk = 0; kk < 128; kk += 32) {
        bf16x8 a;
        if (AF32) {
            const float* Af = (const float*)Av;
            const f32x4* ap = (const f32x4*)(Af + (size_t)rowc * lda + kk + quad * 8);
            f32x4 a0 = ap[0], a1 = ap[1];
#pragma unroll
            for (int j = 0; j < 4; j++) {
                a[j]     = (short)f2bf(a0[j]);
                a[j + 4] = (short)f2bf(a1[j]);
            }
        } else {
            const unsigned short* Ab = (const unsigned short*)Av;
            a = *(const bf16x8*)(Ab + (size_t)rowc * lda + kk + quad * 8);
        }
#pragma unroll
        for (int t = 0; t < 8; t++) {
            bf16x8 b = *(const bf16x8*)(WT + (t * 16 + l16) * 128 + kk + quad * 8);
            acc[t] = __builtin_amdgcn_mfma_f32_16x16x32_bf16(a, b, acc[t], 0, 0, 0);
        }
    }
    // D layout: row = quad*4 + reg, col = l16 (within each 16x16 tile t)
#pragma unroll
    for (int r = 0; r < 4; r++) {
        int orow = rowBase + quad * 4 + r;
        if (orow < M) {
            float di = dinv[orow];
#pragma unroll
            for (int t = 0; t < 8; t++) {
                G[(size_t)orow * 128 + t * 16 + l16] = f2bf(acc[t][r] * di);
            }
        }
    }
}

// ---------- Aggregate v2 ----------
// out[n,:] = relu(dinv[n]*(g[n,:] + sum_{s in N(n)} g[s,:]) + b)
// One wave per node. lane = 16*g + i: group g processes edge slots g, g+4,
// g+8,... (slot e0-1 = self-loop); lane loads channels [8i, 8i+8) as bf16x8
// (16B). Two slots in flight per group (8 edges/wave). After the loop,
// butterfly-reduce across groups (xor 16, 32); group 0 writes the row.
__global__ __launch_bounds__(256) void agg_k(
    const unsigned short* __restrict__ G,
    const int* __restrict__ rp, const int* __restrict__ col,
    const float* __restrict__ dinv, const float* __restrict__ bias,
    float* __restrict__ Out, unsigned short* __restrict__ H,
    int colbase, int N) {
    int gid = (blockIdx.x * blockDim.x + threadIdx.x) >> 6;
    if (gid >= N) return;
    int lane = threadIdx.x & 63;
    int g = lane >> 4, i = lane & 15;

    float acc[8];
#pragma unroll
    for (int j = 0; j < 8; j++) acc[j] = 0.f;

    int e0 = rp[gid], e1 = rp[gid + 1];
    // virtual slot list: index e0-1 == self, then col[e0..e1)
    int my = e0 - 1 + g;
    int c0 = (my < e1) ? ((my >= e0) ? col[my] : gid) : -1; my += 4;
    int c1 = (my < e1) ? ((my >= e0) ? col[my] : gid) : -1; my += 4;

    while (c0 >= 0) {
        int n0 = (my < e1) ? col[my] : -1; my += 4;   // my >= e0+7 here, never self
        int n1 = (my < e1) ? col[my] : -1; my += 4;
        u32x4 v0 = *(const u32x4*)(G + (size_t)c0 * 128 + i * 8);
        if (c1 >= 0) {
            u32x4 v1 = *(const u32x4*)(G + (size_t)c1 * 128 + i * 8);
#pragma unroll
            for (int d = 0; d < 4; d++) {
                acc[2 * d]     += __uint_as_float(v0[d] << 16);
                acc[2 * d + 1] += __uint_as_float(v0[d] & 0xffff0000u);
                acc[2 * d]     += __uint_as_float(v1[d] << 16);
                acc[2 * d + 1] += __uint_as_float(v1[d] & 0xffff0000u);
            }
        } else {
#pragma unroll
            for (int d = 0; d < 4; d++) {
                acc[2 * d]     += __uint_as_float(v0[d] << 16);
                acc[2 * d + 1] += __uint_as_float(v0[d] & 0xffff0000u);
            }
        }
        c0 = n0; c1 = n1;
    }

    // combine the 4 groups
#pragma unroll
    for (int j = 0; j < 8; j++) acc[j] += __shfl_xor(acc[j], 16, 64);
#pragma unroll
    for (int j = 0; j < 8; j++) acc[j] += __shfl_xor(acc[j], 32, 64);

    if (g == 0) {
        float di = dinv[gid];
        const f32x4* bp = (const f32x4*)(bias + i * 8);
        f32x4 b0 = bp[0], b1 = bp[1];
        f32x4 o0, o1;
#pragma unroll
        for (int j = 0; j < 4; j++) {
            o0[j] = fmaxf(acc[j] * di + b0[j], 0.f);
            o1[j] = fmaxf(acc[j + 4] * di + b1[j], 0.f);
        }
        float* orow = Out + (size_t)gid * 256 + colbase + i * 8;
        *(f32x4*)orow = o0;
        *(f32x4*)(orow + 4) = o1;
        if (H) {
            bf16x8 hv;
#pragma unroll
            for (int j = 0; j < 4; j++) {
                hv[j]     = (short)f2bf(o0[j]);
                hv[j + 4] = (short)f2bf(o1[j]);
            }
            *(bf16x8*)(H + (size_t)gid * 128 + i * 8) = hv;
        }
    }
}

extern "C" void kernel_launch(void* const* d_in, const int* in_sizes, int n_in,
                              void* d_out, int out_size, void* d_ws, size_t ws_size,
                              hipStream_t stream) {
    const float* x  = (const float*)d_in[0];   // [N,128] f32
    const float* W1 = (const float*)d_in[1];   // [128,128] f32
    const float* b1 = (const float*)d_in[2];   // [128] f32
    const float* W2 = (const float*)d_in[3];
    const float* b2 = (const float*)d_in[4];
    const int* ei = (const int*)d_in[5];       // [2,E] int32

    const int N = in_sizes[0] / 128;
    const int E = in_sizes[5] / 2;
    const int* src = ei;
    const int* dst = ei + E;

    char* ws = (char*)d_ws;
    int*   cnt  = (int*)(ws + OFF_CNT);
    int*   cur  = (int*)(ws + OFF_CUR);
    int*   rp   = (int*)(ws + OFF_RP);
    int*   bsum = (int*)(ws + OFF_BSUM);
    float* dinv = (float*)(ws + OFF_DINV);
    int*   col  = (int*)(ws + OFF_COL);
    unsigned short* WT1 = (unsigned short*)(ws + OFF_WT1);
    unsigned short* WT2 = (unsigned short*)(ws + OFF_WT2);
    unsigned short* G   = (unsigned short*)(ws + OFF_G);
    unsigned short* H1  = (ws_size >= (size_t)WS_NEED)
                          ? (unsigned short*)(ws + OFF_H1) : nullptr;
    float* out = (float*)d_out;

    hipMemsetAsync(cnt, 0, (size_t)N * sizeof(int), stream);

    transpose_w<<<64, 256, 0, stream>>>(W1, WT1);
    transpose_w<<<64, 256, 0, stream>>>(W2, WT2);

    int ceb = (E + 255) / 256;
    count_k<<<ceb, 256, 0, stream>>>(dst, cnt, E);

    int nb = (N + 255) / 256;
    scan1_k<<<nb, 256, 0, stream>>>(cnt, rp, bsum, N);
    scan2_k<<<1, 512, 0, stream>>>(bsum, nb);
    int nb1 = (N + 1 + 255) / 256;
    scan3_k<<<nb1, 256, 0, stream>>>(rp, bsum, cnt, cur, dinv, N, E);
    fill_k<<<ceb, 256, 0, stream>>>(src, dst, cur, col, E);

    int gb = (N + 63) / 64;
    int ab = (N + 3) / 4;

    // Layer 1 (A = x, f32)
    gemm_scale<1><<<gb, 256, 0, stream>>>(x, 128, WT1, dinv, G, N);
    agg_k<<<ab, 256, 0, stream>>>(G, rp, col, dinv, b1, out, H1, 0, N);
    // Layer 2 (A = h1: bf16 H1 if scratch allows, else f32 rows of out)
    if (H1) {
        gemm_scale<0><<<gb, 256, 0, stream>>>(H1, 128, WT2, dinv, G, N);
    } else {
        gemm_scale<1><<<gb, 256, 0, stream>>>(out, 256, WT2, dinv, G, N);
    }
    agg_k<<<ab, 256, 0, stream>>>(G, rp, col, dinv, b2, out, nullptr, 128, N);
}

// Round 5
// 382.644 us; speedup vs baseline: 1.8354x; 1.3873x over previous
//
#include <hip/hip_runtime.h>
#include <hip/hip_bf16.h>

// GCN encoder: out = concat(h1, h2), h_l = relu(Dinv(A+I)Dinv (x@W_l) + b_l)
// Inputs: x[N,128], W1,W2[128,128], b1,b2[128] = float32; edge_index int32 [2,E]
// Output: float32 [N,256] (harness compares vs bf16-emulated np ref, 2% rel).
//
// Round 5: replace atomic-scatter CSR build (count_k+scan+fill_k, ~105MB of
// partial-line writebacks = 16x amplification) with LDS-binned counting sort:
//   bin_k:  workgroup bins 4096 edges into 196 dst-buckets (512 nodes each)
//           in LDS, bulk-flushes per-bucket runs (full-ish lines).
//   build_k: one workgroup per bucket: LDS count + scan -> rp/dinv coalesced,
//           col scatter confined to the bucket's own 48KB region (own-XCD L2).
// GEMM (MFMA row-tile) and agg (16B gather, 8 edges in flight, shfl butterfly)
// unchanged from round 4.
//
// ws layout (bytes):
#define OFF_GCNT 0x0000000   // int[196]     bucket cursors (memset 0)
#define OFF_RP   0x0001000   // int[N+1]     CSR row pointers
#define OFF_DINV 0x0070000   // float[N]     rsqrt(deg+1)
#define OFF_WT1  0x00E0000   // bf16[128*128] W1^T
#define OFF_WT2  0x00E8000   // bf16[128*128] W2^T
#define OFF_COL  0x00F0000   // int[E]       CSR col (src) ids
#define OFF_G    0x0710000   // overlay: gBuf (9.6MB, dead after build_k) then
                             //          bf16 G[N*128] (25.6MB)
#define OFF_H1   0x1F80000   // bf16[N*128]  h1 staged for layer-2 GEMM
#define WS_NEED  0x3800000   // ~58.7MB if H1 used; 33MB min otherwise

#define CAPL   64      // LDS slots per bucket in bin_k
#define MAXNBK 200     // static LDS sizing (actual NBK=196 for N=100000)
#define CAP2   12288   // global slots per bucket (avg fill 8163, +45 sigma)

typedef short bf16x8 __attribute__((ext_vector_type(8)));
typedef float f32x4 __attribute__((ext_vector_type(4)));
typedef unsigned int u32x4 __attribute__((ext_vector_type(4)));

static __device__ __forceinline__ unsigned short f2bf(float f) {
    unsigned int u = __float_as_uint(f);
    u = u + 0x7fffu + ((u >> 16) & 1u);   // round-to-nearest-even
    return (unsigned short)(u >> 16);
}

// ---------- phase 1: LDS-binned edge bucketing ----------
__global__ __launch_bounds__(256) void bin_k(
    const int* __restrict__ src, const int* __restrict__ dst,
    int* __restrict__ gCnt, unsigned* __restrict__ gBuf, int E, int NBK) {
    __shared__ int lcnt[MAXNBK];
    __shared__ unsigned lbuf[MAXNBK * CAPL];
    for (int i = threadIdx.x; i < NBK; i += 256) lcnt[i] = 0;
    __syncthreads();
    int base = blockIdx.x * 4096;
#pragma unroll 4
    for (int j = 0; j < 16; j++) {
        int e = base + j * 256 + threadIdx.x;
        if (e < E) {
            int d = dst[e], s = src[e];
            int b = d >> 9;
            unsigned entry = ((unsigned)(d & 511) << 23) | (unsigned)s;
            int pos = atomicAdd(&lcnt[b], 1);
            if (pos < CAPL) {
                lbuf[b * CAPL + pos] = entry;
            } else {            // overflow spill (statistically never at CAPL=64)
                int gp = atomicAdd(&gCnt[b], 1);
                if (gp < CAP2) gBuf[(size_t)b * CAP2 + gp] = entry;
            }
        }
    }
    __syncthreads();
    for (int b = threadIdx.x; b < NBK; b += 256) {
        int n = lcnt[b]; if (n > CAPL) n = CAPL;
        if (n) {
            int gp = atomicAdd(&gCnt[b], n);
            for (int k = 0; k < n; k++) {
                int p = gp + k;
                if (p < CAP2) gBuf[(size_t)b * CAP2 + p] = lbuf[b * CAPL + k];
            }
        }
    }
}

// ---------- phase 2: per-bucket counting sort -> rp, dinv, col ----------
__global__ __launch_bounds__(256) void build_k(
    const unsigned* __restrict__ gBuf, const int* __restrict__ gCnt,
    int* __restrict__ rp, float* __restrict__ dinv, int* __restrict__ col,
    int NBK, int N) {
    __shared__ unsigned entries[CAP2];
    __shared__ int bc[256], tmp[256];
    __shared__ int ncnt[512], nrp[512], ncur[512];
    int t = threadIdx.x, b = blockIdx.x;

    // scan bucket counts -> colBase
    int c = (t < NBK) ? gCnt[t] : 0;
    if (c > CAP2) c = CAP2;
    bc[t] = c;
    tmp[t] = c;
    __syncthreads();
    for (int off = 1; off < 256; off <<= 1) {
        int x = (t >= off) ? tmp[t - off] : 0;
        __syncthreads(); tmp[t] += x; __syncthreads();
    }
    int colBase = tmp[b] - bc[b];
    int total = tmp[255];
    int cntb = bc[b];
    if (b == 0 && t == 0) rp[N] = total;

    // load this bucket's entries
    for (int k = t; k < cntb; k += 256) entries[k] = gBuf[(size_t)b * CAP2 + k];
    ncnt[t] = 0; ncnt[t + 256] = 0;
    __syncthreads();

    // pass A: per-node counts
    for (int k = t; k < cntb; k += 256) atomicAdd(&ncnt[entries[k] >> 23], 1);
    __syncthreads();

    // exclusive scan of 512 counts with 256 threads
    int v0 = ncnt[2 * t], v1 = ncnt[2 * t + 1];
    int ps = v0 + v1;
    tmp[t] = ps;
    __syncthreads();
    for (int off = 1; off < 256; off <<= 1) {
        int x = (t >= off) ? tmp[t - off] : 0;
        __syncthreads(); tmp[t] += x; __syncthreads();
    }
    int ex = tmp[t] - ps;
    nrp[2 * t] = ex;          ncur[2 * t] = ex;
    nrp[2 * t + 1] = ex + v0; ncur[2 * t + 1] = ex + v0;
    __syncthreads();

    // rp + dinv (coalesced)
    int g0 = b << 9;
    for (int i = t; i < 512; i += 256) {
        int g = g0 + i;
        if (g < N) {
            rp[g] = colBase + nrp[i];
            dinv[g] = rsqrtf((float)(ncnt[i] + 1));
        }
    }
    __syncthreads();

    // pass B: place into col (scatter confined to this bucket's region)
    for (int k = t; k < cntb; k += 256) {
        unsigned e = entries[k];
        int dl = e >> 23;
        int s = (int)(e & 0x7fffffu);
        int pos = atomicAdd(&ncur[dl], 1);
        col[colBase + pos] = s;
    }
}

// ---------- transpose + cvt W (128x128 f32 -> bf16) ----------
__global__ void transpose_w(const float* __restrict__ W,
                            unsigned short* __restrict__ WT) {
    int idx = blockIdx.x * 256 + threadIdx.x;   // grid 64 -> 16384
    int n = idx >> 7, k = idx & 127;
    WT[idx] = f2bf(W[k * 128 + n]);
}

// ---------- GEMM: G[r,:] = bf16( (A[r,:] @ W) * dinv[r] ) ----------
// AF32=1: A is float32 [M,lda]; AF32=0: A is bf16 (ushort) [M,lda]
template <int AF32>
__global__ __launch_bounds__(256) void gemm_scale(
    const void* __restrict__ Av, int lda,
    const unsigned short* __restrict__ WT,
    const float* __restrict__ dinv,
    unsigned short* __restrict__ G, int M) {
    int wave = threadIdx.x >> 6;
    int lane = threadIdx.x & 63;
    int quad = lane >> 4;
    int l16  = lane & 15;
    int rowBase = blockIdx.x * 64 + wave * 16;
    int rowc = rowBase + l16;
    if (rowc > M - 1) rowc = M - 1;

    f32x4 acc[8];
#pragma unroll
    for (int t = 0; t < 8; t++) acc[t] = (f32x4){0.f, 0.f, 0.f, 0.f};

#pragma unroll
    for (int kk = 0; kk < 128; kk += 32) {
        bf16x8 a;
        if (AF32) {
            const float* Af = (const float*)Av;
            const f32x4* ap = (const f32x4*)(Af + (size_t)rowc * lda + kk + quad * 8);
            f32x4 a0 = ap[0], a1 = ap[1];
#pragma unroll
            for (int j = 0; j < 4; j++) {
                a[j]     = (short)f2bf(a0[j]);
                a[j + 4] = (short)f2bf(a1[j]);
            }
        } else {
            const unsigned short* Ab = (const unsigned short*)Av;
            a = *(const bf16x8*)(Ab + (size_t)rowc * lda + kk + quad * 8);
        }
#pragma unroll
        for (int t = 0; t < 8; t++) {
            bf16x8 b = *(const bf16x8*)(WT + (t * 16 + l16) * 128 + kk + quad * 8);
            acc[t] = __builtin_amdgcn_mfma_f32_16x16x32_bf16(a, b, acc[t], 0, 0, 0);
        }
    }
    // D layout: row = quad*4 + reg, col = l16 (within each 16x16 tile t)
#pragma unroll
    for (int r = 0; r < 4; r++) {
        int orow = rowBase + quad * 4 + r;
        if (orow < M) {
            float di = dinv[orow];
#pragma unroll
            for (int t = 0; t < 8; t++) {
                G[(size_t)orow * 128 + t * 16 + l16] = f2bf(acc[t][r] * di);
            }
        }
    }
}

// ---------- Aggregate ----------
// out[n,:] = relu(dinv[n]*(g[n,:] + sum_{s in N(n)} g[s,:]) + b)
// One wave per node. lane = 16*g + i: group g processes edge slots g, g+4,
// g+8,... (slot e0-1 = self-loop); lane loads channels [8i, 8i+8) as bf16x8
// (16B). Two slots in flight per group (8 edges/wave). After the loop,
// butterfly-reduce across groups (xor 16, 32); group 0 writes the row.
__global__ __launch_bounds__(256) void agg_k(
    const unsigned short* __restrict__ G,
    const int* __restrict__ rp, const int* __restrict__ col,
    const float* __restrict__ dinv, const float* __restrict__ bias,
    float* __restrict__ Out, unsigned short* __restrict__ H,
    int colbase, int N) {
    int gid = (blockIdx.x * blockDim.x + threadIdx.x) >> 6;
    if (gid >= N) return;
    int lane = threadIdx.x & 63;
    int g = lane >> 4, i = lane & 15;

    float acc[8];
#pragma unroll
    for (int j = 0; j < 8; j++) acc[j] = 0.f;

    int e0 = rp[gid], e1 = rp[gid + 1];
    // virtual slot list: index e0-1 == self, then col[e0..e1)
    int my = e0 - 1 + g;
    int c0 = (my < e1) ? ((my >= e0) ? col[my] : gid) : -1; my += 4;
    int c1 = (my < e1) ? ((my >= e0) ? col[my] : gid) : -1; my += 4;

    while (c0 >= 0) {
        int n0 = (my < e1) ? col[my] : -1; my += 4;   // my >= e0+7 here, never self
        int n1 = (my < e1) ? col[my] : -1; my += 4;
        u32x4 v0 = *(const u32x4*)(G + (size_t)c0 * 128 + i * 8);
        if (c1 >= 0) {
            u32x4 v1 = *(const u32x4*)(G + (size_t)c1 * 128 + i * 8);
#pragma unroll
            for (int d = 0; d < 4; d++) {
                acc[2 * d]     += __uint_as_float(v0[d] << 16);
                acc[2 * d + 1] += __uint_as_float(v0[d] & 0xffff0000u);
                acc[2 * d]     += __uint_as_float(v1[d] << 16);
                acc[2 * d + 1] += __uint_as_float(v1[d] & 0xffff0000u);
            }
        } else {
#pragma unroll
            for (int d = 0; d < 4; d++) {
                acc[2 * d]     += __uint_as_float(v0[d] << 16);
                acc[2 * d + 1] += __uint_as_float(v0[d] & 0xffff0000u);
            }
        }
        c0 = n0; c1 = n1;
    }

    // combine the 4 groups
#pragma unroll
    for (int j = 0; j < 8; j++) acc[j] += __shfl_xor(acc[j], 16, 64);
#pragma unroll
    for (int j = 0; j < 8; j++) acc[j] += __shfl_xor(acc[j], 32, 64);

    if (g == 0) {
        float di = dinv[gid];
        const f32x4* bp = (const f32x4*)(bias + i * 8);
        f32x4 b0 = bp[0], b1 = bp[1];
        f32x4 o0, o1;
#pragma unroll
        for (int j = 0; j < 4; j++) {
            o0[j] = fmaxf(acc[j] * di + b0[j], 0.f);
            o1[j] = fmaxf(acc[j + 4] * di + b1[j], 0.f);
        }
        float* orow = Out + (size_t)gid * 256 + colbase + i * 8;
        *(f32x4*)orow = o0;
        *(f32x4*)(orow + 4) = o1;
        if (H) {
            bf16x8 hv;
#pragma unroll
            for (int j = 0; j < 4; j++) {
                hv[j]     = (short)f2bf(o0[j]);
                hv[j + 4] = (short)f2bf(o1[j]);
            }
            *(bf16x8*)(H + (size_t)gid * 128 + i * 8) = hv;
        }
    }
}

extern "C" void kernel_launch(void* const* d_in, const int* in_sizes, int n_in,
                              void* d_out, int out_size, void* d_ws, size_t ws_size,
                              hipStream_t stream) {
    const float* x  = (const float*)d_in[0];   // [N,128] f32
    const float* W1 = (const float*)d_in[1];   // [128,128] f32
    const float* b1 = (const float*)d_in[2];   // [128] f32
    const float* W2 = (const float*)d_in[3];
    const float* b2 = (const float*)d_in[4];
    const int* ei = (const int*)d_in[5];       // [2,E] int32

    const int N = in_sizes[0] / 128;
    const int E = in_sizes[5] / 2;
    const int* src = ei;
    const int* dst = ei + E;
    const int NBK = (N + 511) >> 9;            // 196 for N=100000 (<= MAXNBK)

    char* ws = (char*)d_ws;
    int*      gCnt = (int*)(ws + OFF_GCNT);
    int*      rp   = (int*)(ws + OFF_RP);
    float*    dinv = (float*)(ws + OFF_DINV);
    unsigned short* WT1 = (unsigned short*)(ws + OFF_WT1);
    unsigned short* WT2 = (unsigned short*)(ws + OFF_WT2);
    int*      col  = (int*)(ws + OFF_COL);
    unsigned* gBuf = (unsigned*)(ws + OFF_G);          // dead after build_k
    unsigned short* G = (unsigned short*)(ws + OFF_G); // overlays gBuf
    unsigned short* H1 = (ws_size >= (size_t)WS_NEED)
                         ? (unsigned short*)(ws + OFF_H1) : nullptr;
    float* out = (float*)d_out;

    hipMemsetAsync(gCnt, 0, (size_t)NBK * sizeof(int), stream);

    transpose_w<<<64, 256, 0, stream>>>(W1, WT1);
    transpose_w<<<64, 256, 0, stream>>>(W2, WT2);

    // CSR build: bin then per-bucket counting sort
    bin_k<<<(E + 4095) / 4096, 256, 0, stream>>>(src, dst, gCnt, gBuf, E, NBK);
    build_k<<<NBK, 256, 0, stream>>>(gBuf, gCnt, rp, dinv, col, NBK, N);

    int gb = (N + 63) / 64;
    int ab = (N + 3) / 4;

    // Layer 1 (A = x, f32)
    gemm_scale<1><<<gb, 256, 0, stream>>>(x, 128, WT1, dinv, G, N);
    agg_k<<<ab, 256, 0, stream>>>(G, rp, col, dinv, b1, out, H1, 0, N);
    // Layer 2 (A = h1: bf16 H1 if scratch allows, else f32 rows of out)
    if (H1) {
        gemm_scale<0><<<gb, 256, 0, stream>>>(H1, 128, WT2, dinv, G, N);
    } else {
        gemm_scale<1><<<gb, 256, 0, stream>>>(out, 256, WT2, dinv, G, N);
    }
    agg_k<<<ab, 256, 0, stream>>>(G, rp, col, dinv, b2, out, nullptr, 128, N);
}